// Round 1
// baseline (688.997 us; speedup 1.0000x reference)
//
#include <hip/hip_runtime.h>

#define D 128
#define EDGE_IN 258
#define TI 32

// ---------------- CSR build ----------------
__global__ void zero_int(int* __restrict__ p, int n) {
  int i = blockIdx.x * blockDim.x + threadIdx.x;
  if (i < n) p[i] = 0;
}

__global__ void hist_kernel(const int* __restrict__ dst, int* __restrict__ deg, int ne) {
  int e = blockIdx.x * blockDim.x + threadIdx.x;
  if (e < ne) atomicAdd(&deg[dst[e]], 1);
}

__global__ __launch_bounds__(1024) void scan_kernel(const int* __restrict__ deg,
                                                    int* __restrict__ offs, int n) {
  __shared__ int part[1024];
  int tid = threadIdx.x;
  int IT = (n + 1023) >> 10;
  int base = tid * IT;
  int s = 0;
  for (int j = 0; j < IT; j++) { int idx = base + j; if (idx < n) s += deg[idx]; }
  part[tid] = s;
  __syncthreads();
  for (int off = 1; off < 1024; off <<= 1) {
    int v = (tid >= off) ? part[tid - off] : 0;
    __syncthreads();
    part[tid] += v;
    __syncthreads();
  }
  int run = (tid == 0) ? 0 : part[tid - 1];
  for (int j = 0; j < IT; j++) {
    int idx = base + j;
    if (idx < n) { offs[idx] = run; run += deg[idx]; }
  }
  if (tid == 1023) offs[n] = part[1023];
}

__global__ void copy_kernel(const int* __restrict__ a, int* __restrict__ b, int n) {
  int i = blockIdx.x * blockDim.x + threadIdx.x;
  if (i < n) b[i] = a[i];
}

__global__ void scatter_kernel(const int* __restrict__ dst, int* __restrict__ cur,
                               int* __restrict__ eid, int ne) {
  int e = blockIdx.x * blockDim.x + threadIdx.x;
  if (e < ne) {
    int p = atomicAdd(&cur[dst[e]], 1);
    eid[p] = e;
  }
}

// ---------------- weight transpose ----------------
// WT (float4 view): [L][2(src,dst)][32(k4)][128(d)] ; Wrel: [L][2][128]
__global__ void transpose_kernel(const float* __restrict__ W_emb, float* __restrict__ WT,
                                 float* __restrict__ Wrel) {
  int d = threadIdx.x;      // 0..127
  int k = blockIdx.x;       // 0..127
  int part = blockIdx.y;    // 0,1 = src/dst ; 2 = rel cols
  int l = blockIdx.z;
  if (part < 2) {
    int off = part ? 130 : 0;
    int mat = l * 2 + part;
    WT[((mat * 32 + (k >> 2)) * 128 + d) * 4 + (k & 3)] =
        W_emb[(size_t)(l * D + d) * EDGE_IN + off + k];
  } else if (k < 2) {
    Wrel[(l * 2 + k) * 128 + d] = W_emb[(size_t)(l * D + d) * EDGE_IN + 128 + k];
  }
}

// ---------------- per-actor projections: P_src, P_dst ----------------
__global__ __launch_bounds__(256) void proj_kernel(const float* __restrict__ feat,
                                                   const float4* __restrict__ WT,
                                                   float* __restrict__ Ps,
                                                   float* __restrict__ Pd, int n, int l) {
  __shared__ float lf[TI][D];  // 16 KB
  int i0 = blockIdx.x * TI;
  int tid = threadIdx.x;
  // stage feat tile (coalesced float4)
  for (int t = tid; t < TI * D / 4; t += 256) {
    int fi = t >> 5;  // actor within tile
    int gi = i0 + fi;
    float4 v = (gi < n) ? ((const float4*)feat)[(size_t)gi * (D / 4) + (t & 31)]
                        : make_float4(0.f, 0.f, 0.f, 0.f);
    ((float4*)&lf[0][0])[t] = v;
  }
  __syncthreads();
  int d = tid & (D - 1);
  int g = tid >> 7;  // wave-uniform
  const float4* WsT4 = WT + (size_t)(l * 2 + 0) * 32 * 128;
  const float4* WdT4 = WT + (size_t)(l * 2 + 1) * 32 * 128;
  float accs[16], accd[16];
#pragma unroll
  for (int i = 0; i < 16; i++) { accs[i] = 0.f; accd[i] = 0.f; }
  int ibase = g * 16;
  for (int k4 = 0; k4 < 32; k4++) {
    float4 ws = WsT4[k4 * 128 + d];  // coalesced
    float4 wd = WdT4[k4 * 128 + d];
#pragma unroll
    for (int i = 0; i < 16; i++) {
      float4 f = *(const float4*)&lf[ibase + i][k4 * 4];  // wave-uniform -> LDS broadcast
      accs[i] += f.x * ws.x + f.y * ws.y + f.z * ws.z + f.w * ws.w;
      accd[i] += f.x * wd.x + f.y * wd.y + f.z * wd.z + f.w * wd.w;
    }
  }
#pragma unroll
  for (int i = 0; i < 16; i++) {
    int gi = i0 + ibase + i;
    if (gi < n) {
      Ps[(size_t)gi * D + d] = accs[i];
      Pd[(size_t)gi * D + d] = accd[i];
    }
  }
}

// ---------------- per-actor attention dots: a_src, a_dst ----------------
__global__ __launch_bounds__(256) void att_proj(const float* __restrict__ feat,
                                                const float* __restrict__ W_att,
                                                float* __restrict__ a_s,
                                                float* __restrict__ a_d, int n, int l) {
  int i = blockIdx.x * blockDim.x + threadIdx.x;
  if (i >= n) return;
  const float* Wa = W_att + (size_t)l * EDGE_IN;
  const float4* f = (const float4*)(feat + (size_t)i * D);
  float s = 0.f, t = 0.f;
#pragma unroll 8
  for (int k4 = 0; k4 < 32; k4++) {
    float4 v = f[k4];
    int k = 4 * k4;
    s += v.x * Wa[k] + v.y * Wa[k + 1] + v.z * Wa[k + 2] + v.w * Wa[k + 3];
    t += v.x * Wa[130 + k] + v.y * Wa[131 + k] + v.z * Wa[132 + k] + v.w * Wa[133 + k];
  }
  a_s[i] = s;
  a_d[i] = t;
}

// ---------------- edge pass: one wave per dst, online softmax ----------------
__global__ __launch_bounds__(256) void edge_kernel(
    const float* __restrict__ Ps, const float* __restrict__ Pd,
    const float* __restrict__ a_s, const float* __restrict__ a_d,
    const float* __restrict__ rel, const int* __restrict__ srcIdx,
    const int* __restrict__ offs, const int* __restrict__ eid,
    const float* __restrict__ Wrel, const float* __restrict__ W_att,
    float* __restrict__ out, int n, int l) {
  int wid = (blockIdx.x * blockDim.x + threadIdx.x) >> 6;
  if (wid >= n) return;
  int lane = threadIdx.x & 63;
  int v = wid;
  int d0 = 2 * lane;  // two adjacent dims per lane -> float2 coalesced
  const float2 wc0 = *(const float2*)&Wrel[(l * 2 + 0) * 128 + d0];
  const float2 wc1 = *(const float2*)&Wrel[(l * 2 + 1) * 128 + d0];
  float wax = W_att[(size_t)l * EDGE_IN + 128];
  float way = W_att[(size_t)l * EDGE_IN + 129];
  float ad = a_d[v];
  int p0 = offs[v], p1 = offs[v + 1];
  float m = -1e30f, lsum = 0.f, acc0 = 0.f, acc1 = 0.f;
  for (int p = p0; p < p1; p++) {
    int e = eid[p];            // wave-uniform -> s_load
    int si = srcIdx[e];
    float rx = rel[2 * e], ry = rel[2 * e + 1];
    float s = a_s[si] + ad + rx * wax + ry * way;
    s = (s > 0.f) ? s : 0.2f * s;  // LeakyReLU(0.2)
    float mnew = fmaxf(m, s);
    float corr = __expf(m - mnew);
    float pw = __expf(s - mnew);
    lsum = lsum * corr + pw;
    m = mnew;
    float2 ps = *(const float2*)&Ps[(size_t)si * D + d0];  // 512B/wave gather
    acc0 = acc0 * corr + pw * (ps.x + rx * wc0.x + ry * wc1.x);
    acc1 = acc1 * corr + pw * (ps.y + rx * wc0.y + ry * wc1.y);
  }
  float2 o = make_float2(0.f, 0.f);
  if (p1 > p0) {
    float inv = 1.0f / lsum;
    float2 pd = *(const float2*)&Pd[(size_t)v * D + d0];
    o.x = fmaxf(acc0 * inv + pd.x, 0.f);  // + P_dst (sum(att)==1), then ReLU
    o.y = fmaxf(acc1 * inv + pd.y, 0.f);
  }
  *(float2*)&out[(size_t)v * D + d0] = o;
}

extern "C" void kernel_launch(void* const* d_in, const int* in_sizes, int n_in,
                              void* d_out, int out_size, void* d_ws, size_t ws_size,
                              hipStream_t stream) {
  const float* actor = (const float*)d_in[0];
  const float* rel   = (const float*)d_in[1];
  const float* W_att = (const float*)d_in[2];
  const float* W_emb = (const float*)d_in[3];
  const int* srcIdx  = (const int*)d_in[4];
  const int* dstIdx  = (const int*)d_in[5];
  int n  = in_sizes[0] / D;        // 50000
  int ne = in_sizes[4];            // 800000
  int Lnum = in_sizes[2] / EDGE_IN;  // 2
  float* fout_last = (float*)d_out;

  // workspace carve-up (sizes kept multiples of 16 floats for float4 alignment)
  float* ws = (float*)d_ws;
  size_t o = 0;
  float* Ps  = ws + o; o += (size_t)n * D;
  float* Pd  = ws + o; o += (size_t)n * D;
  float* a_s = ws + o; o += (size_t)n + 64;
  float* a_d = ws + o; o += (size_t)n + 64;
  float* WT  = ws + o; o += (size_t)Lnum * 2 * 128 * 128;
  float* Wre = ws + o; o += (size_t)Lnum * 2 * 128;
  int* ibuf = (int*)(ws + o);
  size_t io = 0;
  int* deg  = ibuf + io; io += n + 64;
  int* offs = ibuf + io; io += n + 64;
  int* cur  = ibuf + io; io += n + 64;
  int* eid  = ibuf + io; io += ne;

  // --- CSR by dst (same every call; ws is re-poisoned, so rebuild) ---
  zero_int<<<(n + 255) / 256, 256, 0, stream>>>(deg, n);
  hist_kernel<<<(ne + 255) / 256, 256, 0, stream>>>(dstIdx, deg, ne);
  scan_kernel<<<1, 1024, 0, stream>>>(deg, offs, n);
  copy_kernel<<<(n + 255) / 256, 256, 0, stream>>>(offs, cur, n);
  scatter_kernel<<<(ne + 255) / 256, 256, 0, stream>>>(dstIdx, cur, eid, ne);
  transpose_kernel<<<dim3(128, 3, Lnum), 128, 0, stream>>>(W_emb, WT, Wre);

  // --- layers; d_out doubles as the intermediate feature buffer ---
  const float* fin = actor;
  for (int l = 0; l < Lnum; l++) {
    proj_kernel<<<(n + TI - 1) / TI, 256, 0, stream>>>(fin, (const float4*)WT, Ps, Pd, n, l);
    att_proj<<<(n + 255) / 256, 256, 0, stream>>>(fin, W_att, a_s, a_d, n, l);
    edge_kernel<<<(n + 3) / 4, 256, 0, stream>>>(Ps, Pd, a_s, a_d, rel, srcIdx, offs, eid,
                                                 Wre, W_att, fout_last, n, l);
    fin = fout_last;  // proj/att of layer l+1 read it before edge overwrites it
  }
}

// Round 2
// 510.059 us; speedup vs baseline: 1.3508x; 1.3508x over previous
//
#include <hip/hip_runtime.h>
#include <hip/hip_fp16.h>

#define D 128
#define EDGE_IN 258
#define TI 32

__device__ __forceinline__ float rl_f(float v, int j) {
  return __int_as_float(__builtin_amdgcn_readlane(__float_as_int(v), j));
}
__device__ __forceinline__ int rl_i(int v, int j) {
  return __builtin_amdgcn_readlane(v, j);
}

// ---------------- CSR build ----------------
__global__ void zero_int(int* __restrict__ p, int n) {
  int i = blockIdx.x * blockDim.x + threadIdx.x;
  if (i < n) p[i] = 0;
}

__global__ void hist_kernel(const int* __restrict__ dst, int* __restrict__ deg, int ne) {
  int e = blockIdx.x * blockDim.x + threadIdx.x;
  if (e < ne) atomicAdd(&deg[dst[e]], 1);
}

__global__ __launch_bounds__(1024) void scan_kernel(const int* __restrict__ deg,
                                                    int* __restrict__ offs,
                                                    int* __restrict__ cur, int n) {
  __shared__ int part[1024];
  int tid = threadIdx.x;
  int IT = (n + 1023) >> 10;
  int base = tid * IT;
  int s = 0;
  for (int j = 0; j < IT; j++) { int idx = base + j; if (idx < n) s += deg[idx]; }
  part[tid] = s;
  __syncthreads();
  for (int off = 1; off < 1024; off <<= 1) {
    int v = (tid >= off) ? part[tid - off] : 0;
    __syncthreads();
    part[tid] += v;
    __syncthreads();
  }
  int run = (tid == 0) ? 0 : part[tid - 1];
  for (int j = 0; j < IT; j++) {
    int idx = base + j;
    if (idx < n) { offs[idx] = run; cur[idx] = run; run += deg[idx]; }
  }
  if (tid == 1023) offs[n] = part[1023];
}

// pre-gather edge metadata into CSR slot order: meta[p] = {src, rx, ry, -}
__global__ void scatter_kernel(const int* __restrict__ dst, const int* __restrict__ srcIdx,
                               const float2* __restrict__ rel, int* __restrict__ cur,
                               float4* __restrict__ meta, int ne) {
  int e = blockIdx.x * blockDim.x + threadIdx.x;
  if (e < ne) {
    int p = atomicAdd(&cur[dst[e]], 1);
    float2 r = rel[e];
    meta[p] = make_float4(__int_as_float(srcIdx[e]), r.x, r.y, 0.f);
  }
}

// ---------------- weight transpose ----------------
// WT (float4 view): [L][2(src,dst)][32(k4)][128(d)] ; Wrel: [L][2][128]
__global__ void transpose_kernel(const float* __restrict__ W_emb, float* __restrict__ WT,
                                 float* __restrict__ Wrel) {
  int d = threadIdx.x;      // 0..127
  int k = blockIdx.x;       // 0..127
  int part = blockIdx.y;    // 0,1 = src/dst ; 2 = rel cols
  int l = blockIdx.z;
  if (part < 2) {
    int off = part ? 130 : 0;
    int mat = l * 2 + part;
    WT[((mat * 32 + (k >> 2)) * 128 + d) * 4 + (k & 3)] =
        W_emb[(size_t)(l * D + d) * EDGE_IN + off + k];
  } else if (k < 2) {
    Wrel[(l * 2 + k) * 128 + d] = W_emb[(size_t)(l * D + d) * EDGE_IN + 128 + k];
  }
}

// ---------------- per-actor projections: P_src(fp16), P_dst(fp32) ----------------
__global__ __launch_bounds__(256) void proj_kernel(const float* __restrict__ feat,
                                                   const float4* __restrict__ WT,
                                                   __half* __restrict__ Ps16,
                                                   float* __restrict__ Pd, int n, int l) {
  __shared__ float lf[TI][D];  // 16 KB
  int i0 = blockIdx.x * TI;
  int tid = threadIdx.x;
  for (int t = tid; t < TI * D / 4; t += 256) {
    int fi = t >> 5;
    int gi = i0 + fi;
    float4 v = (gi < n) ? ((const float4*)feat)[(size_t)gi * (D / 4) + (t & 31)]
                        : make_float4(0.f, 0.f, 0.f, 0.f);
    ((float4*)&lf[0][0])[t] = v;
  }
  __syncthreads();
  int d = tid & (D - 1);
  int g = tid >> 7;  // wave-uniform
  const float4* WsT4 = WT + (size_t)(l * 2 + 0) * 32 * 128;
  const float4* WdT4 = WT + (size_t)(l * 2 + 1) * 32 * 128;
  float accs[16], accd[16];
#pragma unroll
  for (int i = 0; i < 16; i++) { accs[i] = 0.f; accd[i] = 0.f; }
  int ibase = g * 16;
  for (int k4 = 0; k4 < 32; k4++) {
    float4 ws = WsT4[k4 * 128 + d];
    float4 wd = WdT4[k4 * 128 + d];
#pragma unroll
    for (int i = 0; i < 16; i++) {
      float4 f = *(const float4*)&lf[ibase + i][k4 * 4];  // wave-uniform -> broadcast
      accs[i] += f.x * ws.x + f.y * ws.y + f.z * ws.z + f.w * ws.w;
      accd[i] += f.x * wd.x + f.y * wd.y + f.z * wd.z + f.w * wd.w;
    }
  }
#pragma unroll
  for (int i = 0; i < 16; i++) {
    int gi = i0 + ibase + i;
    if (gi < n) {
      Ps16[(size_t)gi * D + d] = __float2half(accs[i]);
      Pd[(size_t)gi * D + d] = accd[i];
    }
  }
}

// ---------------- per-actor attention dots: a_src, a_dst ----------------
__global__ __launch_bounds__(256) void att_proj(const float* __restrict__ feat,
                                                const float* __restrict__ W_att,
                                                float* __restrict__ a_s,
                                                float* __restrict__ a_d, int n, int l) {
  int i = blockIdx.x * blockDim.x + threadIdx.x;
  if (i >= n) return;
  const float* Wa = W_att + (size_t)l * EDGE_IN;
  const float4* f = (const float4*)(feat + (size_t)i * D);
  float s = 0.f, t = 0.f;
#pragma unroll 8
  for (int k4 = 0; k4 < 32; k4++) {
    float4 v = f[k4];
    int k = 4 * k4;
    s += v.x * Wa[k] + v.y * Wa[k + 1] + v.z * Wa[k + 2] + v.w * Wa[k + 3];
    t += v.x * Wa[130 + k] + v.y * Wa[131 + k] + v.z * Wa[132 + k] + v.w * Wa[133 + k];
  }
  a_s[i] = s;
  a_d[i] = t;
}

// ---------------- edge pass: one wave per dst ----------------
// Phase A: lane-parallel scores for a chunk of <=64 edges, wave-reduced softmax.
// Phase B: independent Ps gathers (addresses via readlane broadcast), 4-deep MLP.
__global__ __launch_bounds__(256) void edge_kernel(
    const __half2* __restrict__ Ps, const float* __restrict__ Pd,
    const float* __restrict__ a_s, const float* __restrict__ a_d,
    const float4* __restrict__ meta, const int* __restrict__ offs,
    const float* __restrict__ Wrel, const float* __restrict__ W_att,
    float* __restrict__ out, int n, int l) {
  int wid = (blockIdx.x * blockDim.x + threadIdx.x) >> 6;
  if (wid >= n) return;
  int lane = threadIdx.x & 63;
  int d0 = 2 * lane;
  const float2 wc0 = *(const float2*)&Wrel[(l * 2 + 0) * 128 + d0];
  const float2 wc1 = *(const float2*)&Wrel[(l * 2 + 1) * 128 + d0];
  float wax = W_att[(size_t)l * EDGE_IN + 128];
  float way = W_att[(size_t)l * EDGE_IN + 129];
  float ad = a_d[wid];
  int p0 = offs[wid], p1 = offs[wid + 1];
  float m = -1e30f, lsum = 0.f;
  float accx = 0.f, accy = 0.f;
  for (int c0 = p0; c0 < p1; c0 += 64) {
    int cn = min(64, p1 - c0);
    int si = 0;
    float rx = 0.f, ry = 0.f, s = -1e30f;
    if (lane < cn) {
      float4 mt = meta[c0 + lane];
      si = __float_as_int(mt.x);
      rx = mt.y;
      ry = mt.z;
      float sc = a_s[si] + ad + rx * wax + ry * way;
      s = (sc > 0.f) ? sc : 0.2f * sc;
    }
    float cm = s;
#pragma unroll
    for (int o = 32; o; o >>= 1) cm = fmaxf(cm, __shfl_xor(cm, o, 64));
    float mnew = fmaxf(m, cm);
    float corrOld = __expf(m - mnew);
    float w = (lane < cn) ? __expf(s - mnew) : 0.f;
    float csum = w;
#pragma unroll
    for (int o = 32; o; o >>= 1) csum += __shfl_xor(csum, o, 64);
    lsum = lsum * corrOld + csum;
    accx *= corrOld;
    accy *= corrOld;
    m = mnew;
    int j = 0;
    for (; j + 4 <= cn; j += 4) {
      int s0 = rl_i(si, j), s1 = rl_i(si, j + 1), s2 = rl_i(si, j + 2), s3 = rl_i(si, j + 3);
      float w0 = rl_f(w, j), w1 = rl_f(w, j + 1), w2 = rl_f(w, j + 2), w3 = rl_f(w, j + 3);
      float x0 = rl_f(rx, j), x1 = rl_f(rx, j + 1), x2 = rl_f(rx, j + 2), x3 = rl_f(rx, j + 3);
      float y0 = rl_f(ry, j), y1 = rl_f(ry, j + 1), y2 = rl_f(ry, j + 2), y3 = rl_f(ry, j + 3);
      __half2 h0 = Ps[(size_t)s0 * 64 + lane];
      __half2 h1 = Ps[(size_t)s1 * 64 + lane];
      __half2 h2 = Ps[(size_t)s2 * 64 + lane];
      __half2 h3 = Ps[(size_t)s3 * 64 + lane];
      float2 f0 = __half22float2(h0), f1 = __half22float2(h1);
      float2 f2 = __half22float2(h2), f3 = __half22float2(h3);
      accx += w0 * (f0.x + x0 * wc0.x + y0 * wc1.x);
      accy += w0 * (f0.y + x0 * wc0.y + y0 * wc1.y);
      accx += w1 * (f1.x + x1 * wc0.x + y1 * wc1.x);
      accy += w1 * (f1.y + x1 * wc0.y + y1 * wc1.y);
      accx += w2 * (f2.x + x2 * wc0.x + y2 * wc1.x);
      accy += w2 * (f2.y + x2 * wc0.y + y2 * wc1.y);
      accx += w3 * (f3.x + x3 * wc0.x + y3 * wc1.x);
      accy += w3 * (f3.y + x3 * wc0.y + y3 * wc1.y);
    }
    for (; j < cn; j++) {
      int sj = rl_i(si, j);
      float wj = rl_f(w, j), xj = rl_f(rx, j), yj = rl_f(ry, j);
      float2 fj = __half22float2(Ps[(size_t)sj * 64 + lane]);
      accx += wj * (fj.x + xj * wc0.x + yj * wc1.x);
      accy += wj * (fj.y + xj * wc0.y + yj * wc1.y);
    }
  }
  float2 o2 = make_float2(0.f, 0.f);
  if (p1 > p0) {
    float inv = 1.0f / lsum;
    float2 pd = *(const float2*)&Pd[(size_t)wid * D + d0];
    o2.x = fmaxf(accx * inv + pd.x, 0.f);
    o2.y = fmaxf(accy * inv + pd.y, 0.f);
  }
  *(float2*)&out[(size_t)wid * D + d0] = o2;
}

extern "C" void kernel_launch(void* const* d_in, const int* in_sizes, int n_in,
                              void* d_out, int out_size, void* d_ws, size_t ws_size,
                              hipStream_t stream) {
  const float* actor = (const float*)d_in[0];
  const float* rel   = (const float*)d_in[1];
  const float* W_att = (const float*)d_in[2];
  const float* W_emb = (const float*)d_in[3];
  const int* srcIdx  = (const int*)d_in[4];
  const int* dstIdx  = (const int*)d_in[5];
  int n  = in_sizes[0] / D;          // 50000
  int ne = in_sizes[4];              // 800000
  int Lnum = in_sizes[2] / EDGE_IN;  // 2
  float* fout_last = (float*)d_out;

  // workspace carve-up (meta first for 16B alignment)
  float* ws = (float*)d_ws;
  size_t o = 0;
  float4* meta = (float4*)ws; o += 4 * (size_t)ne;
  float* WT  = ws + o; o += (size_t)Lnum * 2 * 128 * 128;
  float* Wre = ws + o; o += (size_t)Lnum * 2 * 128;
  float* Pd  = ws + o; o += (size_t)n * D;
  float* a_s = ws + o; o += (size_t)n + 64;
  float* a_d = ws + o; o += (size_t)n + 64;
  __half* Ps16 = (__half*)(ws + o); o += (size_t)n * D / 2;
  int* ibuf = (int*)(ws + o);
  size_t io = 0;
  int* deg  = ibuf + io; io += n + 64;
  int* offs = ibuf + io; io += n + 64;
  int* cur  = ibuf + io; io += n + 64;

  // --- CSR by dst with pre-gathered per-edge metadata ---
  zero_int<<<(n + 255) / 256, 256, 0, stream>>>(deg, n);
  hist_kernel<<<(ne + 255) / 256, 256, 0, stream>>>(dstIdx, deg, ne);
  scan_kernel<<<1, 1024, 0, stream>>>(deg, offs, cur, n);
  scatter_kernel<<<(ne + 255) / 256, 256, 0, stream>>>(dstIdx, srcIdx, (const float2*)rel,
                                                       cur, meta, ne);
  transpose_kernel<<<dim3(128, 3, Lnum), 128, 0, stream>>>(W_emb, WT, Wre);

  // --- layers; d_out doubles as the intermediate feature buffer ---
  const float* fin = actor;
  for (int l = 0; l < Lnum; l++) {
    proj_kernel<<<(n + TI - 1) / TI, 256, 0, stream>>>(fin, (const float4*)WT, Ps16, Pd, n, l);
    att_proj<<<(n + 255) / 256, 256, 0, stream>>>(fin, W_att, a_s, a_d, n, l);
    edge_kernel<<<(n + 3) / 4, 256, 0, stream>>>((const __half2*)Ps16, Pd, a_s, a_d, meta,
                                                 offs, Wre, W_att, fout_last, n, l);
    fin = fout_last;
  }
}

// Round 3
// 396.198 us; speedup vs baseline: 1.7390x; 1.2874x over previous
//
#include <hip/hip_runtime.h>
#include <hip/hip_fp16.h>

#define D 128
#define EDGE_IN 258
#define TI 32

__device__ __forceinline__ float rl_f(float v, int j) {
  return __int_as_float(__builtin_amdgcn_readlane(__float_as_int(v), j));
}
__device__ __forceinline__ int rl_i(int v, int j) {
  return __builtin_amdgcn_readlane(v, j);
}

// ---------------- CSR build ----------------
__global__ void zero_int(int* __restrict__ p, int n) {
  int i = blockIdx.x * blockDim.x + threadIdx.x;
  if (i < n) p[i] = 0;
}

__global__ void hist_kernel(const int* __restrict__ dst, int* __restrict__ deg, int ne) {
  int e = blockIdx.x * blockDim.x + threadIdx.x;
  if (e < ne) atomicAdd(&deg[dst[e]], 1);
}

// hierarchical scan: stage 1 — per-block (1024-elem chunk) sums
__global__ __launch_bounds__(256) void scan_part(const int* __restrict__ deg,
                                                 int* __restrict__ bsum, int n) {
  __shared__ int red[256];
  int b = blockIdx.x, tid = threadIdx.x;
  int base = b * 1024 + tid * 4;
  int s = 0;
#pragma unroll
  for (int j = 0; j < 4; j++) { int idx = base + j; if (idx < n) s += deg[idx]; }
  red[tid] = s;
  __syncthreads();
  for (int off = 128; off; off >>= 1) {
    if (tid < off) red[tid] += red[tid + off];
    __syncthreads();
  }
  if (tid == 0) bsum[b] = red[0];
}

// stage 2 — scan the block sums (nb <= 256) in one small block
__global__ __launch_bounds__(256) void scan_bsums(int* __restrict__ bsum, int nb) {
  __shared__ int part[256];
  int tid = threadIdx.x;
  int v = (tid < nb) ? bsum[tid] : 0;
  part[tid] = v;
  __syncthreads();
  for (int off = 1; off < 256; off <<= 1) {
    int t = (tid >= off) ? part[tid - off] : 0;
    __syncthreads();
    part[tid] += t;
    __syncthreads();
  }
  if (tid < nb) bsum[tid] = (tid == 0) ? 0 : part[tid - 1];  // exclusive
}

// stage 3 — per-block rescan + global offset; writes offs and cur
__global__ __launch_bounds__(256) void scan_final(const int* __restrict__ deg,
                                                  const int* __restrict__ bsumex,
                                                  int* __restrict__ offs,
                                                  int* __restrict__ cur, int n, int ne) {
  __shared__ int part[256];
  int b = blockIdx.x, tid = threadIdx.x;
  int base = b * 1024 + tid * 4;
  int v[4];
  int s = 0;
#pragma unroll
  for (int j = 0; j < 4; j++) {
    int idx = base + j;
    v[j] = (idx < n) ? deg[idx] : 0;
    s += v[j];
  }
  part[tid] = s;
  __syncthreads();
  for (int off = 1; off < 256; off <<= 1) {
    int t = (tid >= off) ? part[tid - off] : 0;
    __syncthreads();
    part[tid] += t;
    __syncthreads();
  }
  int run = bsumex[b] + ((tid == 0) ? 0 : part[tid - 1]);
#pragma unroll
  for (int j = 0; j < 4; j++) {
    int idx = base + j;
    if (idx < n) { offs[idx] = run; cur[idx] = run; run += v[j]; }
  }
  if (b == 0 && tid == 0) offs[n] = ne;
}

// pre-gather edge metadata into CSR slot order: meta[p] = {src, rx, ry, -}
__global__ void scatter_kernel(const int* __restrict__ dst, const int* __restrict__ srcIdx,
                               const float2* __restrict__ rel, int* __restrict__ cur,
                               float4* __restrict__ meta, int ne) {
  int e = blockIdx.x * blockDim.x + threadIdx.x;
  if (e < ne) {
    int p = atomicAdd(&cur[dst[e]], 1);
    float2 r = rel[e];
    meta[p] = make_float4(__int_as_float(srcIdx[e]), r.x, r.y, 0.f);
  }
}

// ---------------- weight transpose ----------------
// WT (float4 view): [L][2(src,dst)][32(k4)][128(d)] ; Wrel: [L][2][128]
__global__ void transpose_kernel(const float* __restrict__ W_emb, float* __restrict__ WT,
                                 float* __restrict__ Wrel) {
  int d = threadIdx.x;      // 0..127
  int k = blockIdx.x;       // 0..127
  int part = blockIdx.y;    // 0,1 = src/dst ; 2 = rel cols
  int l = blockIdx.z;
  if (part < 2) {
    int off = part ? 130 : 0;
    int mat = l * 2 + part;
    WT[((mat * 32 + (k >> 2)) * 128 + d) * 4 + (k & 3)] =
        W_emb[(size_t)(l * D + d) * EDGE_IN + off + k];
  } else if (k < 2) {
    Wrel[(l * 2 + k) * 128 + d] = W_emb[(size_t)(l * D + d) * EDGE_IN + 128 + k];
  }
}

// ---------------- per-actor projections: P_src(fp16), P_dst(fp32) ----------------
__global__ __launch_bounds__(256) void proj_kernel(const float* __restrict__ feat,
                                                   const float4* __restrict__ WT,
                                                   __half* __restrict__ Ps16,
                                                   float* __restrict__ Pd, int n, int l) {
  __shared__ float lf[TI][D];  // 16 KB
  int i0 = blockIdx.x * TI;
  int tid = threadIdx.x;
  for (int t = tid; t < TI * D / 4; t += 256) {
    int fi = t >> 5;
    int gi = i0 + fi;
    float4 v = (gi < n) ? ((const float4*)feat)[(size_t)gi * (D / 4) + (t & 31)]
                        : make_float4(0.f, 0.f, 0.f, 0.f);
    ((float4*)&lf[0][0])[t] = v;
  }
  __syncthreads();
  int d = tid & (D - 1);
  int g = tid >> 7;  // wave-uniform
  const float4* WsT4 = WT + (size_t)(l * 2 + 0) * 32 * 128;
  const float4* WdT4 = WT + (size_t)(l * 2 + 1) * 32 * 128;
  float accs[16], accd[16];
#pragma unroll
  for (int i = 0; i < 16; i++) { accs[i] = 0.f; accd[i] = 0.f; }
  int ibase = g * 16;
  for (int k4 = 0; k4 < 32; k4++) {
    float4 ws = WsT4[k4 * 128 + d];
    float4 wd = WdT4[k4 * 128 + d];
#pragma unroll
    for (int i = 0; i < 16; i++) {
      float4 f = *(const float4*)&lf[ibase + i][k4 * 4];  // wave-uniform -> broadcast
      accs[i] += f.x * ws.x + f.y * ws.y + f.z * ws.z + f.w * ws.w;
      accd[i] += f.x * wd.x + f.y * wd.y + f.z * wd.z + f.w * wd.w;
    }
  }
#pragma unroll
  for (int i = 0; i < 16; i++) {
    int gi = i0 + ibase + i;
    if (gi < n) {
      Ps16[(size_t)gi * D + d] = __float2half(accs[i]);
      Pd[(size_t)gi * D + d] = accd[i];
    }
  }
}

// ---------------- per-actor attention dots: a_src, a_dst ----------------
__global__ __launch_bounds__(256) void att_proj(const float* __restrict__ feat,
                                                const float* __restrict__ W_att,
                                                float* __restrict__ a_s,
                                                float* __restrict__ a_d, int n, int l) {
  int i = blockIdx.x * blockDim.x + threadIdx.x;
  if (i >= n) return;
  const float* Wa = W_att + (size_t)l * EDGE_IN;
  const float4* f = (const float4*)(feat + (size_t)i * D);
  float s = 0.f, t = 0.f;
#pragma unroll 8
  for (int k4 = 0; k4 < 32; k4++) {
    float4 v = f[k4];
    int k = 4 * k4;
    s += v.x * Wa[k] + v.y * Wa[k + 1] + v.z * Wa[k + 2] + v.w * Wa[k + 3];
    t += v.x * Wa[130 + k] + v.y * Wa[131 + k] + v.z * Wa[132 + k] + v.w * Wa[133 + k];
  }
  a_s[i] = s;
  a_d[i] = t;
}

// ---------------- edge pass: one wave per dst ----------------
// Phase A: lane-parallel scores for a chunk of <=64 edges, wave-reduced softmax.
// Phase B: independent Ps gathers (addresses via readlane broadcast), 4-deep MLP.
__global__ __launch_bounds__(256) void edge_kernel(
    const __half2* __restrict__ Ps, const float* __restrict__ Pd,
    const float* __restrict__ a_s, const float* __restrict__ a_d,
    const float4* __restrict__ meta, const int* __restrict__ offs,
    const float* __restrict__ Wrel, const float* __restrict__ W_att,
    float* __restrict__ out, int n, int l) {
  int wid = (blockIdx.x * blockDim.x + threadIdx.x) >> 6;
  if (wid >= n) return;
  int lane = threadIdx.x & 63;
  int d0 = 2 * lane;
  const float2 wc0 = *(const float2*)&Wrel[(l * 2 + 0) * 128 + d0];
  const float2 wc1 = *(const float2*)&Wrel[(l * 2 + 1) * 128 + d0];
  float wax = W_att[(size_t)l * EDGE_IN + 128];
  float way = W_att[(size_t)l * EDGE_IN + 129];
  float ad = a_d[wid];
  int p0 = offs[wid], p1 = offs[wid + 1];
  float m = -1e30f, lsum = 0.f;
  float accx = 0.f, accy = 0.f;
  for (int c0 = p0; c0 < p1; c0 += 64) {
    int cn = min(64, p1 - c0);
    int si = 0;
    float rx = 0.f, ry = 0.f, s = -1e30f;
    if (lane < cn) {
      float4 mt = meta[c0 + lane];
      si = __float_as_int(mt.x);
      rx = mt.y;
      ry = mt.z;
      float sc = a_s[si] + ad + rx * wax + ry * way;
      s = (sc > 0.f) ? sc : 0.2f * sc;
    }
    float cm = s;
#pragma unroll
    for (int o = 32; o; o >>= 1) cm = fmaxf(cm, __shfl_xor(cm, o, 64));
    float mnew = fmaxf(m, cm);
    float corrOld = __expf(m - mnew);
    float w = (lane < cn) ? __expf(s - mnew) : 0.f;
    float csum = w;
#pragma unroll
    for (int o = 32; o; o >>= 1) csum += __shfl_xor(csum, o, 64);
    lsum = lsum * corrOld + csum;
    accx *= corrOld;
    accy *= corrOld;
    m = mnew;
    int j = 0;
    for (; j + 4 <= cn; j += 4) {
      int s0 = rl_i(si, j), s1 = rl_i(si, j + 1), s2 = rl_i(si, j + 2), s3 = rl_i(si, j + 3);
      float w0 = rl_f(w, j), w1 = rl_f(w, j + 1), w2 = rl_f(w, j + 2), w3 = rl_f(w, j + 3);
      float x0 = rl_f(rx, j), x1 = rl_f(rx, j + 1), x2 = rl_f(rx, j + 2), x3 = rl_f(rx, j + 3);
      float y0 = rl_f(ry, j), y1 = rl_f(ry, j + 1), y2 = rl_f(ry, j + 2), y3 = rl_f(ry, j + 3);
      __half2 h0 = Ps[(size_t)s0 * 64 + lane];
      __half2 h1 = Ps[(size_t)s1 * 64 + lane];
      __half2 h2 = Ps[(size_t)s2 * 64 + lane];
      __half2 h3 = Ps[(size_t)s3 * 64 + lane];
      float2 f0 = __half22float2(h0), f1 = __half22float2(h1);
      float2 f2 = __half22float2(h2), f3 = __half22float2(h3);
      accx += w0 * (f0.x + x0 * wc0.x + y0 * wc1.x);
      accy += w0 * (f0.y + x0 * wc0.y + y0 * wc1.y);
      accx += w1 * (f1.x + x1 * wc0.x + y1 * wc1.x);
      accy += w1 * (f1.y + x1 * wc0.y + y1 * wc1.y);
      accx += w2 * (f2.x + x2 * wc0.x + y2 * wc1.x);
      accy += w2 * (f2.y + x2 * wc0.y + y2 * wc1.y);
      accx += w3 * (f3.x + x3 * wc0.x + y3 * wc1.x);
      accy += w3 * (f3.y + x3 * wc0.y + y3 * wc1.y);
    }
    for (; j < cn; j++) {
      int sj = rl_i(si, j);
      float wj = rl_f(w, j), xj = rl_f(rx, j), yj = rl_f(ry, j);
      float2 fj = __half22float2(Ps[(size_t)sj * 64 + lane]);
      accx += wj * (fj.x + xj * wc0.x + yj * wc1.x);
      accy += wj * (fj.y + xj * wc0.y + yj * wc1.y);
    }
  }
  float2 o2 = make_float2(0.f, 0.f);
  if (p1 > p0) {
    float inv = 1.0f / lsum;
    float2 pd = *(const float2*)&Pd[(size_t)wid * D + d0];
    o2.x = fmaxf(accx * inv + pd.x, 0.f);
    o2.y = fmaxf(accy * inv + pd.y, 0.f);
  }
  *(float2*)&out[(size_t)wid * D + d0] = o2;
}

extern "C" void kernel_launch(void* const* d_in, const int* in_sizes, int n_in,
                              void* d_out, int out_size, void* d_ws, size_t ws_size,
                              hipStream_t stream) {
  const float* actor = (const float*)d_in[0];
  const float* rel   = (const float*)d_in[1];
  const float* W_att = (const float*)d_in[2];
  const float* W_emb = (const float*)d_in[3];
  const int* srcIdx  = (const int*)d_in[4];
  const int* dstIdx  = (const int*)d_in[5];
  int n  = in_sizes[0] / D;          // 50000
  int ne = in_sizes[4];              // 800000
  int Lnum = in_sizes[2] / EDGE_IN;  // 2
  float* fout_last = (float*)d_out;

  // workspace carve-up (meta first for 16B alignment)
  float* ws = (float*)d_ws;
  size_t o = 0;
  float4* meta = (float4*)ws; o += 4 * (size_t)ne;
  float* WT  = ws + o; o += (size_t)Lnum * 2 * 128 * 128;
  float* Wre = ws + o; o += (size_t)Lnum * 2 * 128;
  float* Pd  = ws + o; o += (size_t)n * D;
  float* a_s = ws + o; o += (size_t)n + 64;
  float* a_d = ws + o; o += (size_t)n + 64;
  __half* Ps16 = (__half*)(ws + o); o += (size_t)n * D / 2;
  int* ibuf = (int*)(ws + o);
  size_t io = 0;
  int* deg  = ibuf + io; io += n + 64;
  int* offs = ibuf + io; io += n + 64;
  int* cur  = ibuf + io; io += n + 64;
  int* bsum = ibuf + io; io += 256;

  int nb = (n + 1023) / 1024;  // 49 chunk-blocks for the scan

  // --- CSR by dst with pre-gathered per-edge metadata ---
  zero_int<<<(n + 255) / 256, 256, 0, stream>>>(deg, n);
  hist_kernel<<<(ne + 255) / 256, 256, 0, stream>>>(dstIdx, deg, ne);
  scan_part<<<nb, 256, 0, stream>>>(deg, bsum, n);
  scan_bsums<<<1, 256, 0, stream>>>(bsum, nb);
  scan_final<<<nb, 256, 0, stream>>>(deg, bsum, offs, cur, n, ne);
  scatter_kernel<<<(ne + 255) / 256, 256, 0, stream>>>(dstIdx, srcIdx, (const float2*)rel,
                                                       cur, meta, ne);
  transpose_kernel<<<dim3(128, 3, Lnum), 128, 0, stream>>>(W_emb, WT, Wre);

  // --- layers; d_out doubles as the intermediate feature buffer ---
  const float* fin = actor;
  for (int l = 0; l < Lnum; l++) {
    proj_kernel<<<(n + TI - 1) / TI, 256, 0, stream>>>(fin, (const float4*)WT, Ps16, Pd, n, l);
    att_proj<<<(n + 255) / 256, 256, 0, stream>>>(fin, W_att, a_s, a_d, n, l);
    edge_kernel<<<(n + 3) / 4, 256, 0, stream>>>((const __half2*)Ps16, Pd, a_s, a_d, meta,
                                                 offs, Wre, W_att, fout_last, n, l);
    fin = fout_last;
  }
}